// Round 6
// baseline (238.603 us; speedup 1.0000x reference)
//
#include <hip/hip_runtime.h>

typedef unsigned short u16;
typedef __bf16 bf16x8_v __attribute__((ext_vector_type(8)));
typedef float f32x4 __attribute__((ext_vector_type(4)));

// ---------- bf16 helpers ----------
__device__ __forceinline__ u16 f2bf(float f) {
    unsigned u = __float_as_uint(f);
    unsigned r = u + 0x7fffu + ((u >> 16) & 1u);   // RNE; inputs finite
    return (u16)(r >> 16);
}
__device__ __forceinline__ float bf2f(u16 h) {
    return __uint_as_float(((unsigned)h) << 16);
}

// async global->LDS, 16B per lane; lds dst = WAVE-UNIFORM base, HW adds lane*16
__device__ __forceinline__ void gll16(const u16* g, u16* l) {
    __builtin_amdgcn_global_load_lds(
        (const __attribute__((address_space(1))) void*)g,
        (__attribute__((address_space(3))) void*)l, 16, 0, 0);
}

#define EXP_SHIFT 12.0f   // fixed-shift softmax: e = exp(score - SHIFT)

// Srow lives in dead space of Sb: rows 0..3 of each batch, cols 1024..2047
// (rows <1024 only ever get cols <1024 written; pv never reads cols>=1024 of
// row-block 0). Row-sum i of batch b -> 512 floats per dead Sb-row.
__device__ __forceinline__ float* srow_ptr(u16* Sb, int b, int i) {
    return (float*)((char*)Sb + (size_t)b * 8388608 +
                    ((i >> 9) << 12) + 2048 + ((size_t)(i & 511) << 2));
}

// ---------------- prep: x->bf16, W->Wt3 bf16 transposed, zero out-upper, zero Srow
// grid 8193 x 256.
__global__ __launch_bounds__(256) void k_prep(const float* __restrict__ x,
                                              const float* __restrict__ Wq,
                                              const float* __restrict__ Wk,
                                              const float* __restrict__ Wv,
                                              u16* __restrict__ xb,
                                              u16* __restrict__ Wt3,
                                              float* __restrict__ out,
                                              u16* __restrict__ Sb) {
    __shared__ float tile[32][33];
    const int bid = blockIdx.x, tid = threadIdx.x;
    if (bid < 4096) {                       // x fp32 -> bf16, 8 elem/thread
        int i = (bid * 256 + tid) * 8;
        float4 a = *(const float4*)(x + i);
        float4 bb = *(const float4*)(x + i + 4);
        union { int4 p; u16 h[8]; } o;
        o.h[0] = f2bf(a.x);  o.h[1] = f2bf(a.y);  o.h[2] = f2bf(a.z);  o.h[3] = f2bf(a.w);
        o.h[4] = f2bf(bb.x); o.h[5] = f2bf(bb.y); o.h[6] = f2bf(bb.z); o.h[7] = f2bf(bb.w);
        *(int4*)(xb + i) = o.p;
    } else if (bid < 7168) {                // W transpose x3 -> Wt3
        const int w = bid - 4096;
        const int z = w >> 10, rem = w & 1023;
        const int bx = rem & 31, by = rem >> 5;
        const float* W = (z == 0) ? Wq : (z == 1) ? Wk : Wv;
        u16* Wt = Wt3 + (size_t)z * 1024 * 1024;
        const int tx = tid & 31, ty = tid >> 5;
#pragma unroll
        for (int r = 0; r < 4; ++r)
            tile[ty + r * 8][tx] = W[(by * 32 + ty + r * 8) * 1024 + bx * 32 + tx];
        __syncthreads();
#pragma unroll
        for (int r = 0; r < 4; ++r)
            Wt[(bx * 32 + ty + r * 8) * 1024 + by * 32 + tx] =
                f2bf(tile[tx][ty + r * 8]);
    } else if (bid < 8192) {                // zero out rows s>=1024 (atomic dst)
        const int c = bid - 7168;           // 1024 blocks x 16 KB
        int4 z4 = {0, 0, 0, 0};
        const int q0 = c * 1024 + tid * 4;  // int4 index, 4 per thread
#pragma unroll
        for (int k = 0; k < 4; ++k) {
            const int q = q0 + k;
            const int b = q >> 18, off = q & 262143;
            *(int4*)(out + (size_t)b * 2097152 + 1048576 + (size_t)off * 4) = z4;
        }
    } else {                                // zero Srow dead-space (32 KB)
        const int chunk = tid >> 7;         // 0..1 within iteration pair
        const int t = tid & 127;
#pragma unroll
        for (int c = 0; c < 8; ++c) {
            const int cc = c * 2 + chunk;   // 0..15: b = cc>>2, r = cc&3
            char* p = (char*)Sb + (size_t)(cc >> 2) * 8388608 +
                      ((cc & 3) << 12) + 2048;
            int4 z4 = {0, 0, 0, 0};
            *(int4*)(p + t * 16) = z4;
        }
    }
}

// ---------------- GEMM core: NT, BK=64, XOR-swizzled LDS ----------------
// C[m][n] = sum_k A[m][k] * Bnt[n][k]. 4 waves (2x2), tile 128x128, BK=64.
// LDS chunk position p of row r holds global chunk p^(r&7).
__device__ __forceinline__ void gemm_core_nt(const u16* __restrict__ A,
                                             const u16* __restrict__ B,
                                             int lda, int ldb, int kLen,
                                             u16* smem, f32x4 acc[4][4]) {
    u16* As = smem;
    u16* Bs = smem + 128 * 64;
    const int tid = threadIdx.x;
    const int wave = tid >> 6;
    const int lane = tid & 63;
    const int rowA = tid >> 3;
    const int kcs  = (tid & 7) ^ (rowA & 7);
    const int row16 = lane & 15;
    const int quad = lane >> 4;
    const int sw = row16 & 7;
    const int wm = (wave >> 1) * 64;
    const int wn = (wave & 1) * 64;

#pragma unroll
    for (int i = 0; i < 4; ++i)
#pragma unroll
        for (int j = 0; j < 4; ++j) {
            f32x4 z = {0.f, 0.f, 0.f, 0.f};
            acc[i][j] = z;
        }

    const u16* Ag[4]; const u16* Bg[4];
    u16 *AsB[4], *BsB[4];
#pragma unroll
    for (int u = 0; u < 4; ++u) {
        Ag[u] = A + (size_t)(u * 32 + rowA) * lda + kcs * 8;
        Bg[u] = B + (size_t)(u * 32 + rowA) * ldb + kcs * 8;
        AsB[u] = As + (u * 256 + wave * 64) * 8;
        BsB[u] = Bs + (u * 256 + wave * 64) * 8;
    }

    const int ktiles = kLen >> 6;
    for (int kt = 0; kt < ktiles; ++kt) {
        __syncthreads();
#pragma unroll
        for (int u = 0; u < 4; ++u) gll16(Ag[u] + kt * 64, AsB[u]);
#pragma unroll
        for (int u = 0; u < 4; ++u) gll16(Bg[u] + kt * 64, BsB[u]);
        __syncthreads();
#pragma unroll
        for (int h = 0; h < 2; ++h) {
            bf16x8_v af[4], bfv[4];
            const int cp = (h * 4 + quad);
#pragma unroll
            for (int i = 0; i < 4; ++i)
                af[i] = *(const bf16x8_v*)(As + (wm + i * 16 + row16) * 64 +
                                           (cp ^ sw) * 8);
#pragma unroll
            for (int j = 0; j < 4; ++j)
                bfv[j] = *(const bf16x8_v*)(Bs + (wn + j * 16 + row16) * 64 +
                                            (cp ^ sw) * 8);
#pragma unroll
            for (int i = 0; i < 4; ++i)
#pragma unroll
                for (int j = 0; j < 4; ++j)
                    acc[i][j] = __builtin_amdgcn_mfma_f32_16x16x32_bf16(
                        af[i], bfv[j], acc[i][j], 0, 0, 0);
        }
    }
}

// Coalesced bf16 epilogue (row-major): wave 64x64 tile via 4 KB LDS slice.
__device__ __forceinline__ void epi_bf16(const f32x4 acc[4][4], u16* smem,
                                         u16* __restrict__ g, int ldg) {
    const int tid = threadIdx.x;
    const int wave = tid >> 6, lane = tid & 63;
    const int row16 = lane & 15, quad = lane >> 4;
    u16* Ts = smem + wave * 2048;
#pragma unroll
    for (int jh = 0; jh < 2; ++jh) {
#pragma unroll
        for (int i = 0; i < 4; ++i)
#pragma unroll
            for (int jj = 0; jj < 2; ++jj) {
                const int j = jh * 2 + jj;
#pragma unroll
                for (int r = 0; r < 4; ++r)
                    Ts[(i * 16 + quad * 4 + r) * 32 + jj * 16 + row16] =
                        f2bf(acc[i][j][r]);
            }
#pragma unroll
        for (int s = 0; s < 4; ++s) {
            const int row = s * 16 + (lane >> 2);
            int4 val = *(const int4*)(Ts + row * 32 + (lane & 3) * 8);
            *(int4*)(g + (size_t)row * ldg + jh * 32 + (lane & 3) * 8) = val;
        }
    }
}

// V-transposed epilogue: wave 64x64 -> Vt[e][s], 16B runs along s.
__device__ __forceinline__ void epi_vt(const f32x4 acc[4][4], u16* smem,
                                       u16* __restrict__ Vt, int m0w, int n0w) {
    const int tid = threadIdx.x;
    const int wave = tid >> 6, lane = tid & 63;
    const int row16 = lane & 15, quad = lane >> 4;
    const int b = m0w >> 11;
    const int sBase = m0w & 2047;
    u16* Ts = smem + wave * 4608;            // 32 x 72 u16
#pragma unroll
    for (int p = 0; p < 2; ++p) {
#pragma unroll
        for (int i = 0; i < 4; ++i)
#pragma unroll
            for (int jj = 0; jj < 2; ++jj) {
                const int j = p * 2 + jj;
                union { unsigned long long d; u16 h[4]; } o;
#pragma unroll
                for (int r = 0; r < 4; ++r) o.h[r] = f2bf(acc[i][j][r]);
                *(unsigned long long*)(Ts + (jj * 16 + row16) * 72 +
                                       i * 16 + quad * 4) = o.d;
            }
#pragma unroll
        for (int rr = 0; rr < 4; ++rr) {
            const int ln = rr * 8 + (lane >> 3);
            const int ck = lane & 7;
            int4 val = *(const int4*)(Ts + ln * 72 + ck * 8);
            const int n = n0w + p * 32 + ln;
            *(int4*)(Vt + ((size_t)b * 1024 + n) * 2048 + sBase + ck * 8) = val;
        }
    }
}

// ---------------- fused QKV projection ----------------
__global__ __launch_bounds__(256, 3) void k_gemm_proj(const u16* __restrict__ X,
                                                      const u16* __restrict__ Wt3,
                                                      u16* __restrict__ Qb,
                                                      u16* __restrict__ Kb,
                                                      u16* __restrict__ Vt) {
    __shared__ u16 smem[18432];              // 36 KB
    const int n0g = blockIdx.x * 128, m0 = blockIdx.y * 128;
    f32x4 acc[4][4];
    gemm_core_nt(X + (size_t)m0 * 1024, Wt3 + (size_t)n0g * 1024, 1024, 1024, 1024,
                 smem, acc);
    const int tid = threadIdx.x, wave = tid >> 6;
    const int wm = (wave >> 1) * 64, wn = (wave & 1) * 64;
    __syncthreads();
    if (n0g < 2048) {
        u16* Y = (n0g < 1024) ? Qb : Kb;
        const int n0 = n0g & 1023;
        epi_bf16(acc, smem, Y + (size_t)(m0 + wm) * 1024 + n0 + wn, 1024);
    } else {
        epi_vt(acc, smem, Vt, m0 + wm, (n0g - 2048) + wn);
    }
}

// Scores + fused unnormalized exp; lower-triangular tiles; grid (136, B).
// Row sums atomicAdd into Srow (dead space inside Sb).
__global__ __launch_bounds__(256, 3) void k_gemm_scores(const u16* __restrict__ Q,
                                                        const u16* __restrict__ Kb,
                                                        u16* __restrict__ Sb) {
    __shared__ u16 smem[16384];
    int t = blockIdx.x, b = blockIdx.y;
    int mt = 0;
    while ((mt + 1) * (mt + 2) / 2 <= t) ++mt;
    int nt = t - mt * (mt + 1) / 2;
    const u16* Qp = Q + (size_t)b * 2048 * 1024 + (size_t)mt * 128 * 1024;
    const u16* Kp = Kb + (size_t)b * 2048 * 1024 + (size_t)nt * 128 * 1024;
    u16* Sp = Sb + (size_t)b * 2048 * 2048;
    f32x4 acc[4][4];
    gemm_core_nt(Qp, Kp, 1024, 1024, 1024, smem, acc);
    const int tid = threadIdx.x, wave = tid >> 6, lane = tid & 63;
    const int wm = (wave >> 1) * 64, wn = (wave & 1) * 64;
    const int row16 = lane & 15, quad = lane >> 4;
    const int mBase = mt * 128 + wm;
    const int nBase = nt * 128 + wn;
    u16* Ts = smem + wave * 2048;
    float rs[4][4];
#pragma unroll
    for (int i = 0; i < 4; ++i)
#pragma unroll
        for (int r = 0; r < 4; ++r) rs[i][r] = 0.f;

    __syncthreads();
#pragma unroll
    for (int jh = 0; jh < 2; ++jh) {
#pragma unroll
        for (int i = 0; i < 4; ++i)
#pragma unroll
            for (int jj = 0; jj < 2; ++jj) {
                const int j = jh * 2 + jj;
                const int n = nBase + jh * 32 + jj * 16 + row16;
#pragma unroll
                for (int r = 0; r < 4; ++r) {
                    const int m = mBase + i * 16 + quad * 4 + r;
                    float e = 0.f;
                    if (n <= m)
                        e = __expf(acc[i][j][r] * 0.03125f - EXP_SHIFT);
                    rs[i][r] += e;
                    Ts[(i * 16 + quad * 4 + r) * 32 + jj * 16 + row16] = f2bf(e);
                }
            }
#pragma unroll
        for (int s = 0; s < 4; ++s) {
            const int row = s * 16 + (lane >> 2);
            int4 val = *(const int4*)(Ts + row * 32 + (lane & 3) * 8);
            *(int4*)(Sp + (size_t)(mBase + row) * 2048 +
                     nBase + jh * 32 + (lane & 3) * 8) = val;
        }
    }
#pragma unroll
    for (int i = 0; i < 4; ++i)
#pragma unroll
        for (int r = 0; r < 4; ++r) {
            float s = rs[i][r];
#pragma unroll
            for (int off = 1; off < 16; off <<= 1) s += __shfl_xor(s, off);
            if (row16 == 0)
                atomicAdd(srow_ptr((u16*)Sb, b, mBase + i * 16 + quad * 4 + r), s);
        }
}

// PV with split-K: mt<8 -> single chunk, direct store; mt>=8 -> two chunks
// (split at K=1024), each atomicAdd-ing inv-scaled partials onto zeroed out.
// grid (8 nt, 24 chunk-slots, B).
__global__ __launch_bounds__(256, 3) void k_gemm_pv(u16* __restrict__ P,
                                                    const u16* __restrict__ Vt,
                                                    float* __restrict__ O) {
    __shared__ u16 smem[16384];
    const int nt = blockIdx.x, b = blockIdx.z;
    const int y = blockIdx.y;
    int mt, c;
    if (y < 16) { mt = 8 + (y >> 1); c = y & 1; }
    else        { mt = y - 16;       c = 0; }
    const int kOff = c << 10;
    const int kLen = min(((mt + 1) << 7) - kOff, 1024);
    const u16* Pp = P + (size_t)b * 2048 * 2048 + (size_t)mt * 128 * 2048 + kOff;
    const u16* Vp = Vt + (size_t)b * 1024 * 2048 + (size_t)nt * 128 * 2048 + kOff;
    f32x4 acc[4][4];
    gemm_core_nt(Pp, Vp, 2048, 2048, kLen, smem, acc);
    float* Op = O + (size_t)b * 2048 * 1024;
    const int tid = threadIdx.x, wave = tid >> 6, lane = tid & 63;
    const int wm = (wave >> 1) * 64, wn = (wave & 1) * 64;
    const int row16 = lane & 15, quad = lane >> 4;
    float inv[4][4];
#pragma unroll
    for (int i = 0; i < 4; ++i)
#pragma unroll
        for (int r = 0; r < 4; ++r)
            inv[i][r] = 1.0f / *srow_ptr(P, b, mt * 128 + wm + i * 16 + quad * 4 + r);
    if (mt < 8) {
#pragma unroll
        for (int i = 0; i < 4; ++i)
#pragma unroll
            for (int j = 0; j < 4; ++j) {
                int m = mt * 128 + wm + i * 16 + quad * 4;
                int n = nt * 128 + wn + j * 16 + row16;
#pragma unroll
                for (int r = 0; r < 4; ++r)
                    Op[(size_t)(m + r) * 1024 + n] = acc[i][j][r] * inv[i][r];
            }
    } else {
#pragma unroll
        for (int i = 0; i < 4; ++i)
#pragma unroll
            for (int j = 0; j < 4; ++j) {
                int m = mt * 128 + wm + i * 16 + quad * 4;
                int n = nt * 128 + wn + j * 16 + row16;
#pragma unroll
                for (int r = 0; r < 4; ++r)
                    atomicAdd(&Op[(size_t)(m + r) * 1024 + n],
                              acc[i][j][r] * inv[i][r]);
            }
    }
}

// ---------------- launcher ----------------
extern "C" void kernel_launch(void* const* d_in, const int* in_sizes, int n_in,
                              void* d_out, int out_size, void* d_ws, size_t ws_size,
                              hipStream_t stream) {
    const float* x  = (const float*)d_in[0];
    const float* Wq = (const float*)d_in[1];
    const float* Wk = (const float*)d_in[2];
    const float* Wv = (const float*)d_in[3];
    float* out = (float*)d_out;
    char* ws = (char*)d_ws;

    u16* xb  = (u16*)(ws);                          // 16 MB: x bf16 [8192,1024]
    u16* Wt3 = (u16*)(ws + (16u << 20));            //  6 MB
    u16* Qb  = (u16*)(ws + (22u << 20));            // 16 MB
    u16* Kb  = (u16*)(ws + (38u << 20));            // 16 MB
    u16* Vt  = (u16*)(ws + (54u << 20));            // 16 MB: V^T [B,1024,2048]
    u16* Sb  = (u16*)(ws + (70u << 20));            // 32 MB: P' (+Srow dead space)

    k_prep<<<8193, 256, 0, stream>>>(x, Wq, Wk, Wv, xb, Wt3, out, Sb);
    k_gemm_proj<<<dim3(24, 64), 256, 0, stream>>>(xb, Wt3, Qb, Kb, Vt);
    k_gemm_scores<<<dim3(136, 4), 256, 0, stream>>>(Qb, Kb, Sb);
    k_gemm_pv<<<dim3(8, 24, 4), 256, 0, stream>>>(Sb, Vt, out);
}

// Round 7
// 234.070 us; speedup vs baseline: 1.0194x; 1.0194x over previous
//
#include <hip/hip_runtime.h>

typedef unsigned short u16;
typedef __bf16 bf16x8_v __attribute__((ext_vector_type(8)));
typedef float f32x4 __attribute__((ext_vector_type(4)));

// ---------- bf16 helpers ----------
__device__ __forceinline__ u16 f2bf(float f) {
    unsigned u = __float_as_uint(f);
    unsigned r = u + 0x7fffu + ((u >> 16) & 1u);   // RNE; inputs finite
    return (u16)(r >> 16);
}
__device__ __forceinline__ float bf2f(u16 h) {
    return __uint_as_float(((unsigned)h) << 16);
}

// async global->LDS, 16B per lane; lds dst = WAVE-UNIFORM base, HW adds lane*16
__device__ __forceinline__ void gll16(const u16* g, u16* l) {
    __builtin_amdgcn_global_load_lds(
        (const __attribute__((address_space(1))) void*)g,
        (__attribute__((address_space(3))) void*)l, 16, 0, 0);
}

#define EXP_SHIFT 12.0f   // fixed-shift softmax: e = exp(score - SHIFT)

// Srow lives in dead space of Sb: rows 0..3 of each batch, cols 1024..1535
// (row-block 0 only ever has cols <128 written/read by scores/pv).
__device__ __forceinline__ float* srow_ptr(u16* Sb, int b, int i) {
    return (float*)((char*)Sb + (size_t)b * 8388608 +
                    ((i >> 9) << 12) + 2048 + ((size_t)(i & 511) << 2));
}

// ---------------- prep: x->bf16, W->Wt3 bf16 transposed, zero Srow ----------
// grid 7169 x 256.
__global__ __launch_bounds__(256) void k_prep(const float* __restrict__ x,
                                              const float* __restrict__ Wq,
                                              const float* __restrict__ Wk,
                                              const float* __restrict__ Wv,
                                              u16* __restrict__ xb,
                                              u16* __restrict__ Wt3,
                                              u16* __restrict__ Sb) {
    __shared__ float tile[32][33];
    const int bid = blockIdx.x, tid = threadIdx.x;
    if (bid < 4096) {                       // x fp32 -> bf16, 8 elem/thread
        int i = (bid * 256 + tid) * 8;
        float4 a = *(const float4*)(x + i);
        float4 bb = *(const float4*)(x + i + 4);
        union { int4 p; u16 h[8]; } o;
        o.h[0] = f2bf(a.x);  o.h[1] = f2bf(a.y);  o.h[2] = f2bf(a.z);  o.h[3] = f2bf(a.w);
        o.h[4] = f2bf(bb.x); o.h[5] = f2bf(bb.y); o.h[6] = f2bf(bb.z); o.h[7] = f2bf(bb.w);
        *(int4*)(xb + i) = o.p;
    } else if (bid < 7168) {                // W transpose x3 -> Wt3
        const int w = bid - 4096;
        const int z = w >> 10, rem = w & 1023;
        const int bx = rem & 31, by = rem >> 5;
        const float* W = (z == 0) ? Wq : (z == 1) ? Wk : Wv;
        u16* Wt = Wt3 + (size_t)z * 1024 * 1024;
        const int tx = tid & 31, ty = tid >> 5;
#pragma unroll
        for (int r = 0; r < 4; ++r)
            tile[ty + r * 8][tx] = W[(by * 32 + ty + r * 8) * 1024 + bx * 32 + tx];
        __syncthreads();
#pragma unroll
        for (int r = 0; r < 4; ++r)
            Wt[(bx * 32 + ty + r * 8) * 1024 + by * 32 + tx] =
                f2bf(tile[tx][ty + r * 8]);
    } else {                                // zero Srow dead-space (32 KB)
        const int chunk = tid >> 7;
        const int t = tid & 127;
#pragma unroll
        for (int c = 0; c < 8; ++c) {
            const int cc = c * 2 + chunk;   // 0..15: b = cc>>2, r = cc&3
            char* p = (char*)Sb + (size_t)(cc >> 2) * 8388608 +
                      ((cc & 3) << 12) + 2048;
            int4 z4 = {0, 0, 0, 0};
            *(int4*)(p + t * 16) = z4;
        }
    }
}

// ---------------- GEMM core: NT, BK=64, XOR-swizzled LDS ----------------
// C[m][n] = sum_k A[m][k] * Bnt[n][k]. 4 waves (2x2), tile 128x128, BK=64.
// LDS chunk position p of row r holds global chunk p^(r&7).
__device__ __forceinline__ void gemm_core_nt(const u16* __restrict__ A,
                                             const u16* __restrict__ B,
                                             int lda, int ldb, int kLen,
                                             u16* smem, f32x4 acc[4][4]) {
    u16* As = smem;
    u16* Bs = smem + 128 * 64;
    const int tid = threadIdx.x;
    const int wave = tid >> 6;
    const int lane = tid & 63;
    const int rowA = tid >> 3;
    const int kcs  = (tid & 7) ^ (rowA & 7);
    const int row16 = lane & 15;
    const int quad = lane >> 4;
    const int sw = row16 & 7;
    const int wm = (wave >> 1) * 64;
    const int wn = (wave & 1) * 64;

#pragma unroll
    for (int i = 0; i < 4; ++i)
#pragma unroll
        for (int j = 0; j < 4; ++j) {
            f32x4 z = {0.f, 0.f, 0.f, 0.f};
            acc[i][j] = z;
        }

    const u16* Ag[4]; const u16* Bg[4];
    u16 *AsB[4], *BsB[4];
#pragma unroll
    for (int u = 0; u < 4; ++u) {
        Ag[u] = A + (size_t)(u * 32 + rowA) * lda + kcs * 8;
        Bg[u] = B + (size_t)(u * 32 + rowA) * ldb + kcs * 8;
        AsB[u] = As + (u * 256 + wave * 64) * 8;
        BsB[u] = Bs + (u * 256 + wave * 64) * 8;
    }

    const int ktiles = kLen >> 6;
    for (int kt = 0; kt < ktiles; ++kt) {
        __syncthreads();
#pragma unroll
        for (int u = 0; u < 4; ++u) gll16(Ag[u] + kt * 64, AsB[u]);
#pragma unroll
        for (int u = 0; u < 4; ++u) gll16(Bg[u] + kt * 64, BsB[u]);
        __syncthreads();
#pragma unroll
        for (int h = 0; h < 2; ++h) {
            bf16x8_v af[4], bfv[4];
            const int cp = (h * 4 + quad);
#pragma unroll
            for (int i = 0; i < 4; ++i)
                af[i] = *(const bf16x8_v*)(As + (wm + i * 16 + row16) * 64 +
                                           (cp ^ sw) * 8);
#pragma unroll
            for (int j = 0; j < 4; ++j)
                bfv[j] = *(const bf16x8_v*)(Bs + (wn + j * 16 + row16) * 64 +
                                            (cp ^ sw) * 8);
#pragma unroll
            for (int i = 0; i < 4; ++i)
#pragma unroll
                for (int j = 0; j < 4; ++j)
                    acc[i][j] = __builtin_amdgcn_mfma_f32_16x16x32_bf16(
                        af[i], bfv[j], acc[i][j], 0, 0, 0);
        }
    }
}

// Coalesced bf16 epilogue (row-major): wave 64x64 tile via 4 KB LDS slice.
__device__ __forceinline__ void epi_bf16(const f32x4 acc[4][4], u16* smem,
                                         u16* __restrict__ g, int ldg) {
    const int tid = threadIdx.x;
    const int wave = tid >> 6, lane = tid & 63;
    const int row16 = lane & 15, quad = lane >> 4;
    u16* Ts = smem + wave * 2048;
#pragma unroll
    for (int jh = 0; jh < 2; ++jh) {
#pragma unroll
        for (int i = 0; i < 4; ++i)
#pragma unroll
            for (int jj = 0; jj < 2; ++jj) {
                const int j = jh * 2 + jj;
#pragma unroll
                for (int r = 0; r < 4; ++r)
                    Ts[(i * 16 + quad * 4 + r) * 32 + jj * 16 + row16] =
                        f2bf(acc[i][j][r]);
            }
#pragma unroll
        for (int s = 0; s < 4; ++s) {
            const int row = s * 16 + (lane >> 2);
            int4 val = *(const int4*)(Ts + row * 32 + (lane & 3) * 8);
            *(int4*)(g + (size_t)row * ldg + jh * 32 + (lane & 3) * 8) = val;
        }
    }
}

// V-transposed epilogue: wave 64x64 -> Vt[e][s], 16B runs along s.
__device__ __forceinline__ void epi_vt(const f32x4 acc[4][4], u16* smem,
                                       u16* __restrict__ Vt, int m0w, int n0w) {
    const int tid = threadIdx.x;
    const int wave = tid >> 6, lane = tid & 63;
    const int row16 = lane & 15, quad = lane >> 4;
    const int b = m0w >> 11;
    const int sBase = m0w & 2047;
    u16* Ts = smem + wave * 4608;            // 32 x 72 u16
#pragma unroll
    for (int p = 0; p < 2; ++p) {
#pragma unroll
        for (int i = 0; i < 4; ++i)
#pragma unroll
            for (int jj = 0; jj < 2; ++jj) {
                const int j = p * 2 + jj;
                union { unsigned long long d; u16 h[4]; } o;
#pragma unroll
                for (int r = 0; r < 4; ++r) o.h[r] = f2bf(acc[i][j][r]);
                *(unsigned long long*)(Ts + (jj * 16 + row16) * 72 +
                                       i * 16 + quad * 4) = o.d;
            }
#pragma unroll
        for (int rr = 0; rr < 4; ++rr) {
            const int ln = rr * 8 + (lane >> 3);
            const int ck = lane & 7;
            int4 val = *(const int4*)(Ts + ln * 72 + ck * 8);
            const int n = n0w + p * 32 + ln;
            *(int4*)(Vt + ((size_t)b * 1024 + n) * 2048 + sBase + ck * 8) = val;
        }
    }
}

// ---------------- fused QKV projection ----------------
__global__ __launch_bounds__(256, 3) void k_gemm_proj(const u16* __restrict__ X,
                                                      const u16* __restrict__ Wt3,
                                                      u16* __restrict__ Qb,
                                                      u16* __restrict__ Kb,
                                                      u16* __restrict__ Vt) {
    __shared__ u16 smem[18432];              // 36 KB
    const int n0g = blockIdx.x * 128, m0 = blockIdx.y * 128;
    f32x4 acc[4][4];
    gemm_core_nt(X + (size_t)m0 * 1024, Wt3 + (size_t)n0g * 1024, 1024, 1024, 1024,
                 smem, acc);
    const int tid = threadIdx.x, wave = tid >> 6;
    const int wm = (wave >> 1) * 64, wn = (wave & 1) * 64;
    __syncthreads();
    if (n0g < 2048) {
        u16* Y = (n0g < 1024) ? Qb : Kb;
        const int n0 = n0g & 1023;
        epi_bf16(acc, smem, Y + (size_t)(m0 + wm) * 1024 + n0 + wn, 1024);
    } else {
        epi_vt(acc, smem, Vt, m0 + wm, (n0g - 2048) + wn);
    }
}

// Scores + fused unnormalized exp; lower-triangular tiles; grid (136, B).
// Row sums atomicAdd into Srow (dead space inside Sb).
__global__ __launch_bounds__(256, 3) void k_gemm_scores(const u16* __restrict__ Q,
                                                        const u16* __restrict__ Kb,
                                                        u16* __restrict__ Sb) {
    __shared__ u16 smem[16384];
    int t = blockIdx.x, b = blockIdx.y;
    int mt = 0;
    while ((mt + 1) * (mt + 2) / 2 <= t) ++mt;
    int nt = t - mt * (mt + 1) / 2;
    const u16* Qp = Q + (size_t)b * 2048 * 1024 + (size_t)mt * 128 * 1024;
    const u16* Kp = Kb + (size_t)b * 2048 * 1024 + (size_t)nt * 128 * 1024;
    u16* Sp = Sb + (size_t)b * 2048 * 2048;
    f32x4 acc[4][4];
    gemm_core_nt(Qp, Kp, 1024, 1024, 1024, smem, acc);
    const int tid = threadIdx.x, wave = tid >> 6, lane = tid & 63;
    const int wm = (wave >> 1) * 64, wn = (wave & 1) * 64;
    const int row16 = lane & 15, quad = lane >> 4;
    const int mBase = mt * 128 + wm;
    const int nBase = nt * 128 + wn;
    u16* Ts = smem + wave * 2048;
    float rs[4][4];
#pragma unroll
    for (int i = 0; i < 4; ++i)
#pragma unroll
        for (int r = 0; r < 4; ++r) rs[i][r] = 0.f;

    __syncthreads();
#pragma unroll
    for (int jh = 0; jh < 2; ++jh) {
#pragma unroll
        for (int i = 0; i < 4; ++i)
#pragma unroll
            for (int jj = 0; jj < 2; ++jj) {
                const int j = jh * 2 + jj;
                const int n = nBase + jh * 32 + jj * 16 + row16;
#pragma unroll
                for (int r = 0; r < 4; ++r) {
                    const int m = mBase + i * 16 + quad * 4 + r;
                    float e = 0.f;
                    if (n <= m)
                        e = __expf(acc[i][j][r] * 0.03125f - EXP_SHIFT);
                    rs[i][r] += e;
                    Ts[(i * 16 + quad * 4 + r) * 32 + jj * 16 + row16] = f2bf(e);
                }
            }
#pragma unroll
        for (int s = 0; s < 4; ++s) {
            const int row = s * 16 + (lane >> 2);
            int4 val = *(const int4*)(Ts + row * 32 + (lane & 3) * 8);
            *(int4*)(Sp + (size_t)(mBase + row) * 2048 +
                     nBase + jh * 32 + (lane & 3) * 8) = val;
        }
    }
#pragma unroll
    for (int i = 0; i < 4; ++i)
#pragma unroll
        for (int r = 0; r < 4; ++r) {
            float s = rs[i][r];
#pragma unroll
            for (int off = 1; off < 16; off <<= 1) s += __shfl_xor(s, off);
            if (row16 == 0)
                atomicAdd(srow_ptr((u16*)Sb, b, mBase + i * 16 + quad * 4 + r), s);
        }
}

// PV with balanced split-K, atomic-free.
// grid (8 nt, 24, B): y<16 -> mt = 8+(y>>1), chunk c=y&1 (ktile halves
// ceil/floor of (mt+1)/2; chains 4..8 ktiles) -> inv-scaled fp32 partial in
// fragment layout to P0/P1 scratch. y>=16 -> mt = y-16 (chain 1..8),
// direct normalized store.
__global__ __launch_bounds__(256, 3) void k_gemm_pv(u16* __restrict__ P,
                                                    const u16* __restrict__ Vt,
                                                    float* __restrict__ O,
                                                    float* __restrict__ P0,
                                                    float* __restrict__ P1) {
    __shared__ u16 smem[16384];
    const int nt = blockIdx.x, b = blockIdx.z;
    const int y = blockIdx.y;
    int mt, kOff, kLen;
    if (y < 16) {
        mt = 8 + (y >> 1);
        const int half0 = (mt + 2) >> 1;            // ktiles (128-col units)
        if ((y & 1) == 0) { kOff = 0;          kLen = half0 << 7; }
        else              { kOff = half0 << 7; kLen = ((mt + 1) << 7) - kOff; }
    } else {
        mt = y - 16; kOff = 0; kLen = (mt + 1) << 7;
    }
    const u16* Pp = P + (size_t)b * 2048 * 2048 + (size_t)mt * 128 * 2048 + kOff;
    const u16* Vp = Vt + (size_t)b * 1024 * 2048 + (size_t)nt * 128 * 2048 + kOff;
    f32x4 acc[4][4];
    gemm_core_nt(Pp, Vp, 2048, 2048, kLen, smem, acc);
    const int tid = threadIdx.x, wave = tid >> 6, lane = tid & 63;
    const int wm = (wave >> 1) * 64, wn = (wave & 1) * 64;
    const int row16 = lane & 15, quad = lane >> 4;
    float inv[4][4];
#pragma unroll
    for (int i = 0; i < 4; ++i)
#pragma unroll
        for (int r = 0; r < 4; ++r)
            inv[i][r] = 1.0f / *srow_ptr(P, b, mt * 128 + wm + i * 16 + quad * 4 + r);
    if (y >= 16) {
        float* Op = O + (size_t)b * 2048 * 1024;
#pragma unroll
        for (int i = 0; i < 4; ++i)
#pragma unroll
            for (int j = 0; j < 4; ++j) {
                int m = mt * 128 + wm + i * 16 + quad * 4;
                int n = nt * 128 + wn + j * 16 + row16;
#pragma unroll
                for (int r = 0; r < 4; ++r)
                    Op[(size_t)(m + r) * 1024 + n] = acc[i][j][r] * inv[i][r];
            }
    } else {
        // partial tile index 0..255; layout: float4 slot k*256+tid, k=0..15
        float* dst = ((y & 1) == 0 ? P0 : P1) +
                     (size_t)(((b * 8 + (mt - 8)) * 8 + nt)) * 16384;
#pragma unroll
        for (int k = 0; k < 16; ++k) {
            const int i = k >> 2, j = k & 3;
            f32x4 sv;
#pragma unroll
            for (int r = 0; r < 4; ++r) sv[r] = acc[i][j][r] * inv[i][r];
            *(f32x4*)(dst + (size_t)(k * 256 + tid) * 4) = sv;
        }
    }
}

// Combine split-K partials: out = P0 + P1 (both already inv-scaled).
// grid 256 blocks (one per mt>=8 tile) x 256 thr.
__global__ __launch_bounds__(256) void k_pv_combine(const float* __restrict__ P0,
                                                    const float* __restrict__ P1,
                                                    float* __restrict__ O) {
    const int t = blockIdx.x;
    const int b = t >> 6, mt = 8 + ((t >> 3) & 7), nt = t & 7;
    const int tid = threadIdx.x, wave = tid >> 6, lane = tid & 63;
    const int wm = (wave >> 1) * 64, wn = (wave & 1) * 64;
    const int row16 = lane & 15, quad = lane >> 4;
    const float* p0 = P0 + (size_t)t * 16384;
    const float* p1 = P1 + (size_t)t * 16384;
    float* Op = O + (size_t)b * 2048 * 1024;
#pragma unroll
    for (int k = 0; k < 16; ++k) {
        f32x4 a = *(const f32x4*)(p0 + (size_t)(k * 256 + tid) * 4);
        f32x4 c = *(const f32x4*)(p1 + (size_t)(k * 256 + tid) * 4);
        const int i = k >> 2, j = k & 3;
        const int m = mt * 128 + wm + i * 16 + quad * 4;
        const int n = nt * 128 + wn + j * 16 + row16;
#pragma unroll
        for (int r = 0; r < 4; ++r)
            Op[(size_t)(m + r) * 1024 + n] = a[r] + c[r];
    }
}

// ---------------- launcher ----------------
extern "C" void kernel_launch(void* const* d_in, const int* in_sizes, int n_in,
                              void* d_out, int out_size, void* d_ws, size_t ws_size,
                              hipStream_t stream) {
    const float* x  = (const float*)d_in[0];
    const float* Wq = (const float*)d_in[1];
    const float* Wk = (const float*)d_in[2];
    const float* Wv = (const float*)d_in[3];
    float* out = (float*)d_out;
    char* ws = (char*)d_ws;

    u16* xb  = (u16*)(ws);                          // 16 MB: x bf16 [8192,1024]
    u16* Wt3 = (u16*)(ws + (16u << 20));            //  6 MB
    u16* Qb  = (u16*)(ws + (22u << 20));            // 16 MB (dead after scores)
    u16* Kb  = (u16*)(ws + (38u << 20));            // 16 MB (dead after scores)
    u16* Vt  = (u16*)(ws + (54u << 20));            // 16 MB: V^T [B,1024,2048]
    u16* Sb  = (u16*)(ws + (70u << 20));            // 32 MB: P' (+Srow dead space)
    float* P0 = (float*)Qb;                         // split-K partials chunk 0
    float* P1 = (float*)Kb;                         // split-K partials chunk 1

    k_prep<<<7169, 256, 0, stream>>>(x, Wq, Wk, Wv, xb, Wt3, Sb);
    k_gemm_proj<<<dim3(24, 64), 256, 0, stream>>>(xb, Wt3, Qb, Kb, Vt);
    k_gemm_scores<<<dim3(136, 4), 256, 0, stream>>>(Qb, Kb, Sb);
    k_gemm_pv<<<dim3(8, 24, 4), 256, 0, stream>>>(Sb, Vt, out, P0, P1);
    k_pv_combine<<<256, 256, 0, stream>>>(P0, P1, out);
}

// Round 8
// 225.570 us; speedup vs baseline: 1.0578x; 1.0377x over previous
//
#include <hip/hip_runtime.h>

typedef unsigned short u16;
typedef __bf16 bf16x8_v __attribute__((ext_vector_type(8)));
typedef float f32x4 __attribute__((ext_vector_type(4)));

// ---------- bf16 helpers ----------
__device__ __forceinline__ u16 f2bf(float f) {
    unsigned u = __float_as_uint(f);
    unsigned r = u + 0x7fffu + ((u >> 16) & 1u);   // RNE; inputs finite
    return (u16)(r >> 16);
}
__device__ __forceinline__ float bf2f(u16 h) {
    return __uint_as_float(((unsigned)h) << 16);
}

// async global->LDS, 16B per lane; lds dst = WAVE-UNIFORM base, HW adds lane*16
__device__ __forceinline__ void gll16(const u16* g, u16* l) {
    __builtin_amdgcn_global_load_lds(
        (const __attribute__((address_space(1))) void*)g,
        (__attribute__((address_space(3))) void*)l, 16, 0, 0);
}

#define EXP_SHIFT 12.0f   // fixed-shift softmax: e = exp(score - SHIFT)

// Srow lives in dead space of Sb: rows 0..3 of each batch, cols 1024..1535
// (row-block 0 only ever has cols <128 written/read by scores/pv).
__device__ __forceinline__ float* srow_ptr(u16* Sb, int b, int i) {
    return (float*)((char*)Sb + (size_t)b * 8388608 +
                    ((i >> 9) << 12) + 2048 + ((size_t)(i & 511) << 2));
}

// ---------------- prep: x->bf16, W->Wt3 bf16 transposed, zero Srow ----------
// grid 7169 x 256.
__global__ __launch_bounds__(256) void k_prep(const float* __restrict__ x,
                                              const float* __restrict__ Wq,
                                              const float* __restrict__ Wk,
                                              const float* __restrict__ Wv,
                                              u16* __restrict__ xb,
                                              u16* __restrict__ Wt3,
                                              u16* __restrict__ Sb) {
    __shared__ float tile[32][33];
    const int bid = blockIdx.x, tid = threadIdx.x;
    if (bid < 4096) {                       // x fp32 -> bf16, 8 elem/thread
        int i = (bid * 256 + tid) * 8;
        float4 a = *(const float4*)(x + i);
        float4 bb = *(const float4*)(x + i + 4);
        union { int4 p; u16 h[8]; } o;
        o.h[0] = f2bf(a.x);  o.h[1] = f2bf(a.y);  o.h[2] = f2bf(a.z);  o.h[3] = f2bf(a.w);
        o.h[4] = f2bf(bb.x); o.h[5] = f2bf(bb.y); o.h[6] = f2bf(bb.z); o.h[7] = f2bf(bb.w);
        *(int4*)(xb + i) = o.p;
    } else if (bid < 7168) {                // W transpose x3 -> Wt3
        const int w = bid - 4096;
        const int z = w >> 10, rem = w & 1023;
        const int bx = rem & 31, by = rem >> 5;
        const float* W = (z == 0) ? Wq : (z == 1) ? Wk : Wv;
        u16* Wt = Wt3 + (size_t)z * 1024 * 1024;
        const int tx = tid & 31, ty = tid >> 5;
#pragma unroll
        for (int r = 0; r < 4; ++r)
            tile[ty + r * 8][tx] = W[(by * 32 + ty + r * 8) * 1024 + bx * 32 + tx];
        __syncthreads();
#pragma unroll
        for (int r = 0; r < 4; ++r)
            Wt[(bx * 32 + ty + r * 8) * 1024 + by * 32 + tx] =
                f2bf(tile[tx][ty + r * 8]);
    } else {                                // zero Srow dead-space (32 KB)
        const int chunk = tid >> 7;
        const int t = tid & 127;
#pragma unroll
        for (int c = 0; c < 8; ++c) {
            const int cc = c * 2 + chunk;   // 0..15: b = cc>>2, r = cc&3
            char* p = (char*)Sb + (size_t)(cc >> 2) * 8388608 +
                      ((cc & 3) << 12) + 2048;
            int4 z4 = {0, 0, 0, 0};
            *(int4*)(p + t * 16) = z4;
        }
    }
}

// ---------------- GEMM core: NT, BK=64, XOR-swizzled LDS ----------------
// C[m][n] = sum_k A[m][k] * Bnt[n][k]. 4 waves (2x2), tile 128x128, BK=64.
// LDS chunk position p of row r holds global chunk p^(r&7).
__device__ __forceinline__ void gemm_core_nt(const u16* __restrict__ A,
                                             const u16* __restrict__ B,
                                             int lda, int ldb, int kLen,
                                             u16* smem, f32x4 acc[4][4]) {
    u16* As = smem;
    u16* Bs = smem + 128 * 64;
    const int tid = threadIdx.x;
    const int wave = tid >> 6;
    const int lane = tid & 63;
    const int rowA = tid >> 3;
    const int kcs  = (tid & 7) ^ (rowA & 7);
    const int row16 = lane & 15;
    const int quad = lane >> 4;
    const int sw = row16 & 7;
    const int wm = (wave >> 1) * 64;
    const int wn = (wave & 1) * 64;

#pragma unroll
    for (int i = 0; i < 4; ++i)
#pragma unroll
        for (int j = 0; j < 4; ++j) {
            f32x4 z = {0.f, 0.f, 0.f, 0.f};
            acc[i][j] = z;
        }

    const u16* Ag[4]; const u16* Bg[4];
    u16 *AsB[4], *BsB[4];
#pragma unroll
    for (int u = 0; u < 4; ++u) {
        Ag[u] = A + (size_t)(u * 32 + rowA) * lda + kcs * 8;
        Bg[u] = B + (size_t)(u * 32 + rowA) * ldb + kcs * 8;
        AsB[u] = As + (u * 256 + wave * 64) * 8;
        BsB[u] = Bs + (u * 256 + wave * 64) * 8;
    }

    const int ktiles = kLen >> 6;
    for (int kt = 0; kt < ktiles; ++kt) {
        __syncthreads();
#pragma unroll
        for (int u = 0; u < 4; ++u) gll16(Ag[u] + kt * 64, AsB[u]);
#pragma unroll
        for (int u = 0; u < 4; ++u) gll16(Bg[u] + kt * 64, BsB[u]);
        __syncthreads();
#pragma unroll
        for (int h = 0; h < 2; ++h) {
            bf16x8_v af[4], bfv[4];
            const int cp = (h * 4 + quad);
#pragma unroll
            for (int i = 0; i < 4; ++i)
                af[i] = *(const bf16x8_v*)(As + (wm + i * 16 + row16) * 64 +
                                           (cp ^ sw) * 8);
#pragma unroll
            for (int j = 0; j < 4; ++j)
                bfv[j] = *(const bf16x8_v*)(Bs + (wn + j * 16 + row16) * 64 +
                                            (cp ^ sw) * 8);
#pragma unroll
            for (int i = 0; i < 4; ++i)
#pragma unroll
                for (int j = 0; j < 4; ++j)
                    acc[i][j] = __builtin_amdgcn_mfma_f32_16x16x32_bf16(
                        af[i], bfv[j], acc[i][j], 0, 0, 0);
        }
    }
}

// Coalesced bf16 epilogue (row-major): wave 64x64 tile via 4 KB LDS slice.
__device__ __forceinline__ void epi_bf16(const f32x4 acc[4][4], u16* smem,
                                         u16* __restrict__ g, int ldg) {
    const int tid = threadIdx.x;
    const int wave = tid >> 6, lane = tid & 63;
    const int row16 = lane & 15, quad = lane >> 4;
    u16* Ts = smem + wave * 2048;
#pragma unroll
    for (int jh = 0; jh < 2; ++jh) {
#pragma unroll
        for (int i = 0; i < 4; ++i)
#pragma unroll
            for (int jj = 0; jj < 2; ++jj) {
                const int j = jh * 2 + jj;
#pragma unroll
                for (int r = 0; r < 4; ++r)
                    Ts[(i * 16 + quad * 4 + r) * 32 + jj * 16 + row16] =
                        f2bf(acc[i][j][r]);
            }
#pragma unroll
        for (int s = 0; s < 4; ++s) {
            const int row = s * 16 + (lane >> 2);
            int4 val = *(const int4*)(Ts + row * 32 + (lane & 3) * 8);
            *(int4*)(g + (size_t)row * ldg + jh * 32 + (lane & 3) * 8) = val;
        }
    }
}

// V-transposed epilogue: wave 64x64 -> Vt[e][s], 16B runs along s.
__device__ __forceinline__ void epi_vt(const f32x4 acc[4][4], u16* smem,
                                       u16* __restrict__ Vt, int m0w, int n0w) {
    const int tid = threadIdx.x;
    const int wave = tid >> 6, lane = tid & 63;
    const int row16 = lane & 15, quad = lane >> 4;
    const int b = m0w >> 11;
    const int sBase = m0w & 2047;
    u16* Ts = smem + wave * 4608;            // 32 x 72 u16
#pragma unroll
    for (int p = 0; p < 2; ++p) {
#pragma unroll
        for (int i = 0; i < 4; ++i)
#pragma unroll
            for (int jj = 0; jj < 2; ++jj) {
                const int j = p * 2 + jj;
                union { unsigned long long d; u16 h[4]; } o;
#pragma unroll
                for (int r = 0; r < 4; ++r) o.h[r] = f2bf(acc[i][j][r]);
                *(unsigned long long*)(Ts + (jj * 16 + row16) * 72 +
                                       i * 16 + quad * 4) = o.d;
            }
#pragma unroll
        for (int rr = 0; rr < 4; ++rr) {
            const int ln = rr * 8 + (lane >> 3);
            const int ck = lane & 7;
            int4 val = *(const int4*)(Ts + ln * 72 + ck * 8);
            const int n = n0w + p * 32 + ln;
            *(int4*)(Vt + ((size_t)b * 1024 + n) * 2048 + sBase + ck * 8) = val;
        }
    }
}

// ---------------- fused QKV projection ----------------
__global__ __launch_bounds__(256, 3) void k_gemm_proj(const u16* __restrict__ X,
                                                      const u16* __restrict__ Wt3,
                                                      u16* __restrict__ Qb,
                                                      u16* __restrict__ Kb,
                                                      u16* __restrict__ Vt) {
    __shared__ u16 smem[18432];              // 36 KB
    const int n0g = blockIdx.x * 128, m0 = blockIdx.y * 128;
    f32x4 acc[4][4];
    gemm_core_nt(X + (size_t)m0 * 1024, Wt3 + (size_t)n0g * 1024, 1024, 1024, 1024,
                 smem, acc);
    const int tid = threadIdx.x, wave = tid >> 6;
    const int wm = (wave >> 1) * 64, wn = (wave & 1) * 64;
    __syncthreads();
    if (n0g < 2048) {
        u16* Y = (n0g < 1024) ? Qb : Kb;
        const int n0 = n0g & 1023;
        epi_bf16(acc, smem, Y + (size_t)(m0 + wm) * 1024 + n0 + wn, 1024);
    } else {
        epi_vt(acc, smem, Vt, m0 + wm, (n0g - 2048) + wn);
    }
}

// Scores + fused unnormalized exp; lower-triangular tiles; grid (136, B).
// Row sums atomicAdd into Srow (dead space inside Sb).
__global__ __launch_bounds__(256, 4) void k_gemm_scores(const u16* __restrict__ Q,
                                                        const u16* __restrict__ Kb,
                                                        u16* __restrict__ Sb) {
    __shared__ u16 smem[16384];
    int t = blockIdx.x, b = blockIdx.y;
    int mt = 0;
    while ((mt + 1) * (mt + 2) / 2 <= t) ++mt;
    int nt = t - mt * (mt + 1) / 2;
    const u16* Qp = Q + (size_t)b * 2048 * 1024 + (size_t)mt * 128 * 1024;
    const u16* Kp = Kb + (size_t)b * 2048 * 1024 + (size_t)nt * 128 * 1024;
    u16* Sp = Sb + (size_t)b * 2048 * 2048;
    f32x4 acc[4][4];
    gemm_core_nt(Qp, Kp, 1024, 1024, 1024, smem, acc);
    const int tid = threadIdx.x, wave = tid >> 6, lane = tid & 63;
    const int wm = (wave >> 1) * 64, wn = (wave & 1) * 64;
    const int row16 = lane & 15, quad = lane >> 4;
    const int mBase = mt * 128 + wm;
    const int nBase = nt * 128 + wn;
    u16* Ts = smem + wave * 2048;
    float rs[4][4];
#pragma unroll
    for (int i = 0; i < 4; ++i)
#pragma unroll
        for (int r = 0; r < 4; ++r) rs[i][r] = 0.f;

    __syncthreads();
#pragma unroll
    for (int jh = 0; jh < 2; ++jh) {
#pragma unroll
        for (int i = 0; i < 4; ++i)
#pragma unroll
            for (int jj = 0; jj < 2; ++jj) {
                const int j = jh * 2 + jj;
                const int n = nBase + jh * 32 + jj * 16 + row16;
#pragma unroll
                for (int r = 0; r < 4; ++r) {
                    const int m = mBase + i * 16 + quad * 4 + r;
                    float e = 0.f;
                    if (n <= m)
                        e = __expf(acc[i][j][r] * 0.03125f - EXP_SHIFT);
                    rs[i][r] += e;
                    Ts[(i * 16 + quad * 4 + r) * 32 + jj * 16 + row16] = f2bf(e);
                }
            }
#pragma unroll
        for (int s = 0; s < 4; ++s) {
            const int row = s * 16 + (lane >> 2);
            int4 val = *(const int4*)(Ts + row * 32 + (lane & 3) * 8);
            *(int4*)(Sp + (size_t)(mBase + row) * 2048 +
                     nBase + jh * 32 + (lane & 3) * 8) = val;
        }
    }
#pragma unroll
    for (int i = 0; i < 4; ++i)
#pragma unroll
        for (int r = 0; r < 4; ++r) {
            float s = rs[i][r];
#pragma unroll
            for (int off = 1; off < 16; off <<= 1) s += __shfl_xor(s, off);
            if (row16 == 0)
                atomicAdd(srow_ptr((u16*)Sb, b, mBase + i * 16 + quad * 4 + r), s);
        }
}

// PV simple: O = (1/Srow) * P'.V; k-extent (mt+1)*128.
// grid (8 nt, 16, B); longest-K first (mt reversed) to shrink the tail.
__global__ __launch_bounds__(256, 4) void k_gemm_pv(u16* __restrict__ P,
                                                    const u16* __restrict__ Vt,
                                                    float* __restrict__ O) {
    __shared__ u16 smem[16384];
    const int nt = blockIdx.x, mt = 15 - blockIdx.y, b = blockIdx.z;
    const u16* Pp = P + (size_t)b * 2048 * 2048 + (size_t)mt * 128 * 2048;
    const u16* Vp = Vt + (size_t)b * 1024 * 2048 + (size_t)nt * 128 * 2048;
    f32x4 acc[4][4];
    gemm_core_nt(Pp, Vp, 2048, 2048, (mt + 1) * 128, smem, acc);
    float* Op = O + (size_t)b * 2048 * 1024;
    const int tid = threadIdx.x, wave = tid >> 6, lane = tid & 63;
    const int wm = (wave >> 1) * 64, wn = (wave & 1) * 64;
    const int row16 = lane & 15, quad = lane >> 4;
    float inv[4][4];
#pragma unroll
    for (int i = 0; i < 4; ++i)
#pragma unroll
        for (int r = 0; r < 4; ++r)
            inv[i][r] = 1.0f / *srow_ptr(P, b, mt * 128 + wm + i * 16 + quad * 4 + r);
#pragma unroll
    for (int i = 0; i < 4; ++i)
#pragma unroll
        for (int j = 0; j < 4; ++j) {
            int m = mt * 128 + wm + i * 16 + quad * 4;
            int n = nt * 128 + wn + j * 16 + row16;
#pragma unroll
            for (int r = 0; r < 4; ++r)
                Op[(size_t)(m + r) * 1024 + n] = acc[i][j][r] * inv[i][r];
        }
}

// ---------------- launcher ----------------
extern "C" void kernel_launch(void* const* d_in, const int* in_sizes, int n_in,
                              void* d_out, int out_size, void* d_ws, size_t ws_size,
                              hipStream_t stream) {
    const float* x  = (const float*)d_in[0];
    const float* Wq = (const float*)d_in[1];
    const float* Wk = (const float*)d_in[2];
    const float* Wv = (const float*)d_in[3];
    float* out = (float*)d_out;
    char* ws = (char*)d_ws;

    u16* xb  = (u16*)(ws);                          // 16 MB: x bf16 [8192,1024]
    u16* Wt3 = (u16*)(ws + (16u << 20));            //  6 MB
    u16* Qb  = (u16*)(ws + (22u << 20));            // 16 MB
    u16* Kb  = (u16*)(ws + (38u << 20));            // 16 MB
    u16* Vt  = (u16*)(ws + (54u << 20));            // 16 MB: V^T [B,1024,2048]
    u16* Sb  = (u16*)(ws + (70u << 20));            // 32 MB: P' (+Srow dead space)

    k_prep<<<7169, 256, 0, stream>>>(x, Wq, Wk, Wv, xb, Wt3, Sb);
    k_gemm_proj<<<dim3(24, 64), 256, 0, stream>>>(xb, Wt3, Qb, Kb, Vt);
    k_gemm_scores<<<dim3(136, 4), 256, 0, stream>>>(Qb, Kb, Sb);
    k_gemm_pv<<<dim3(8, 16, 4), 256, 0, stream>>>(Sb, Vt, out);
}